// Round 12
// baseline (2049.581 us; speedup 1.0000x reference)
//
#include <hip/hip_runtime.h>
#include <hip/hip_bf16.h>
#include <math.h>

// PAFM fused v6: weights as per-lane global fragments (pre-swizzled bf16 pool),
// 70KB LDS -> 2 blocks/CU, 16B staging writes, conflict-free yn store.
// Inputs fp32 dict order; output fp32. Grid 2048 x 512 thr (block = 64 patches).

typedef short short8 __attribute__((ext_vector_type(8)));
typedef float f32x4 __attribute__((ext_vector_type(4)));
typedef unsigned uint4v __attribute__((ext_vector_type(4)));

__device__ __forceinline__ unsigned bf16r(float x) {
    unsigned u = __float_as_uint(x);
    return (u + 0x7FFFu + ((u >> 16) & 1u)) >> 16;
}
__device__ __forceinline__ unsigned pack2(float a, float b) {
    return bf16r(a) | (bf16r(b) << 16);
}
__device__ __forceinline__ float ubf(unsigned short h) {
    return __uint_as_float(((unsigned)h) << 16);
}

// ---------------- kernel 1: per-(side,b,channel) spatial mean of x_low ----------------
__global__ __launch_bounds__(256) void mean_kernel(const float* __restrict__ x_l,
                                                   const float* __restrict__ x_r,
                                                   float* __restrict__ ws_mean) {
    int bid = blockIdx.x;
    const float* src = (bid >= 1024) ? x_r : x_l;
    const float* p = src + (size_t)(bid & 1023) * 16384;
    int t = threadIdx.x;
    float acc = 0.f;
    #pragma unroll 4
    for (int i = t; i < 16384; i += 256) acc += p[i];
    #pragma unroll
    for (int off = 32; off > 0; off >>= 1) acc += __shfl_down(acc, off, 64);
    __shared__ float red[4];
    if ((t & 63) == 0) red[t >> 6] = acc;
    __syncthreads();
    if (t == 0) ws_mean[bid] = (red[0] + red[1] + red[2] + red[3]) * (1.f / 16384.f);
}

// ---------------- kernel 2: channel gate cm[side][b][128] ----------------
__global__ __launch_bounds__(128) void cm_kernel(const float* __restrict__ ws_mean,
                                                 float* __restrict__ ws_cm,
                                                 const float* __restrict__ Wk,
                                                 const float* __restrict__ bk,
                                                 const float* __restrict__ d_w1,
                                                 const float* __restrict__ d_ln2_g,
                                                 const float* __restrict__ d_ln2_b,
                                                 const float* __restrict__ d_w2) {
    int sb = blockIdx.x;
    __shared__ float km[128];
    int o = threadIdx.x;
    const float* mu = ws_mean + sb * 256;
    float acc = bk[o];
    for (int c = 0; c < 256; ++c) acc = fmaf(Wk[o * 256 + c], mu[c], acc);
    km[o] = acc;
    __syncthreads();
    int h = o >> 4, d = o & 15;
    float t1[8];
    #pragma unroll
    for (int r = 0; r < 8; ++r) {
        float a = 0.f;
        #pragma unroll
        for (int dd = 0; dd < 16; ++dd) a = fmaf(d_w1[r * 16 + dd], km[h * 16 + dd], a);
        t1[r] = a / (1.f + expf(-a));
    }
    float m = 0.f;
    #pragma unroll
    for (int r = 0; r < 8; ++r) m += t1[r];
    m *= 0.125f;
    float v = 0.f;
    #pragma unroll
    for (int r = 0; r < 8; ++r) { float df = t1[r] - m; v = fmaf(df, df, v); }
    float rstd = rsqrtf(v * 0.125f + 1e-5f);
    float cmv = 0.f;
    #pragma unroll
    for (int r = 0; r < 8; ++r)
        cmv = fmaf((t1[r] - m) * rstd * d_ln2_g[r] + d_ln2_b[r], d_w2[d * 8 + r], cmv);
    ws_cm[sb * 128 + o] = cmv;
}

// ---------------- kernel 2b: weights -> bf16 pre-swizzled pool in ws ----------------
// pool (u16): WK=0 [4][32][256]; WV=32768; WQ=65536 [2][64][128]; WQV=81920; WP=98304
__global__ __launch_bounds__(256) void wprep(const float* __restrict__ Wq,
                                             const float* __restrict__ Wqv,
                                             const float* __restrict__ Wk,
                                             const float* __restrict__ Wv,
                                             const float* __restrict__ Wp,
                                             unsigned short* __restrict__ wsp) {
    int bid = blockIdx.x, t = threadIdx.x;
    if (bid < 64) {
        const float* src = (bid < 32) ? Wk : Wv;
        unsigned short* dst = wsp + ((bid < 32) ? 0 : 32768);
        int base = (bid & 31) * 1024;
        #pragma unroll
        for (int i = 0; i < 4; ++i) {
            int el = base + t + 256 * i;
            int q = el >> 13, rem = el & 8191, op = rem >> 8, col = rem & 255;
            dst[q * 8192 + op * 256 + (col ^ ((op & 7) << 3))] =
                (unsigned short)bf16r(src[(q * 32 + op) * 256 + col]);
        }
    } else {
        int g = (bid - 64) >> 4;
        const float* src = (g == 0) ? Wq : (g == 1) ? Wqv : Wp;
        unsigned short* dst = wsp + 65536 + g * 16384;
        int base = ((bid - 64) & 15) * 1024;
        #pragma unroll
        for (int i = 0; i < 4; ++i) {
            int el = base + t + 256 * i;
            int hf = el >> 13, rem = el & 8191, op = rem >> 7, col = rem & 127;
            dst[hf * 8192 + op * 128 + (col ^ ((op & 7) << 3))] =
                (unsigned short)bf16r(src[(hf * 64 + op) * 128 + col]);
        }
    }
}

// LDS offsets (u16)
#define O_XA 0       // 16384: x_low 64x256 / x_high 128x128 / xc / yn
#define O_K  16384   // 8192: [64][128]
#define O_V  24576   // 8192
#define O_LG 32768   // 2048: [256 rows][8 heads]
#define O_SM 34816   // 1024 u16 = 512 f32
#define LDS_U16 35840 // 70 KB

__device__ __forceinline__ short8 frag(const unsigned short* lds, int off, int row, int k, int C2) {
    return *(const short8*)&lds[off + row * C2 + (k ^ ((row & 7) << 3))];
}
__device__ __forceinline__ short8 wfrag(const unsigned short* __restrict__ p, int row, int k, int C2) {
    return *(const short8*)&p[row * C2 + (k ^ ((row & 7) << 3))];
}

// stage fp32 tile -> bf16 LDS, 16B/lane writes (conflict-optimal), coalesced global reads
template<int R, int C2>
__device__ __forceinline__ void stageA16(const float* __restrict__ g, size_t cstride,
                                         unsigned short* lds, int off, int t) {
    #pragma unroll
    for (int it = 0; it < (R * (C2 / 8)) / 512; ++it) {
        int idx = t + it * 512;
        int rr = idx & (R - 1);
        int bc = idx / R;
        float v0 = g[(size_t)(8 * bc + 0) * cstride + rr];
        float v1 = g[(size_t)(8 * bc + 1) * cstride + rr];
        float v2 = g[(size_t)(8 * bc + 2) * cstride + rr];
        float v3 = g[(size_t)(8 * bc + 3) * cstride + rr];
        float v4 = g[(size_t)(8 * bc + 4) * cstride + rr];
        float v5 = g[(size_t)(8 * bc + 5) * cstride + rr];
        float v6 = g[(size_t)(8 * bc + 6) * cstride + rr];
        float v7 = g[(size_t)(8 * bc + 7) * cstride + rr];
        uint4v u = {pack2(v0, v1), pack2(v2, v3), pack2(v4, v5), pack2(v6, v7)};
        *(uint4v*)&lds[off + rr * C2 + ((bc ^ (rr & 7)) << 3)] = u;
    }
}

#define ZERO4(A) do { _Pragma("unroll") for (int z_ = 0; z_ < 4; ++z_) A[z_] = (f32x4){0.f,0.f,0.f,0.f}; } while (0)

#define CONSUME(ACC, DY, NH) do {                                                  \
    _Pragma("unroll")                                                              \
    for (int n_ = 0; n_ < 4; ++n_) {                                               \
      int nt_ = 4 * (NH) + n_;                                                     \
      int o_ = 16 * nt_ + lm;                                                      \
      float bias_ = bq[o_];                                                        \
      float sd01_ = 0.f, sd23_ = 0.f;                                              \
      _Pragma("unroll")                                                            \
      for (int r_ = 0; r_ < 4; ++r_) {                                             \
        int row_ = 16 * w + 4 * lg + r_;                                           \
        int tok_ = row_ >> 1;                                                      \
        float q_ = ACC[n_][r_] + bias_;                                            \
        float kv_ = ubf(lds[O_K + tok_ * 128 + (o_ ^ ((tok_ & 7) << 3))]);         \
        float t0_ = q_, t1_ = q_ * q_, t2_ = q_ * gw, t3_ = q_ * kv_;              \
        _Pragma("unroll")                                                          \
        for (int d_ = 1; d_ < 16; d_ <<= 1) {                                      \
          t0_ += __shfl_xor(t0_, d_, 64); t1_ += __shfl_xor(t1_, d_, 64);          \
          t2_ += __shfl_xor(t2_, d_, 64); t3_ += __shfl_xor(t3_, d_, 64);          \
        }                                                                          \
        float mn_ = t0_ * 0.0625f;                                                 \
        float rs_ = rsqrtf(t1_ * 0.0625f - mn_ * mn_ + 1e-5f);                     \
        float sdt_ = rs_ * (t2_ - mn_ * S1) + S2;                                  \
        if (r_ < 2) sd01_ += sdt_; else sd23_ += sdt_;                             \
        if (lm == r_) lds[O_LG + ((DY) * 128 + row_) * 8 + nt_] = (unsigned short)bf16r(t3_ * 0.25f); \
      }                                                                            \
      if (lm == 0) smf[(8 * w + 2 * lg) * 8 + nt_]     += sd01_;                   \
      if (lm == 1) smf[(8 * w + 2 * lg + 1) * 8 + nt_] += sd23_;                   \
    } } while (0)

#define COMBINE(ACC, DY, NH) do {                                                  \
    _Pragma("unroll")                                                              \
    for (int n_ = 0; n_ < 4; ++n_) {                                               \
      int nt_ = 4 * (NH) + n_;                                                     \
      int o_ = 16 * nt_ + lm;                                                      \
      float bias_ = bqv[o_];                                                       \
      float cmv_ = cmp[o_];                                                        \
      _Pragma("unroll")                                                            \
      for (int r_ = 0; r_ < 4; ++r_) {                                             \
        int row_ = 16 * w + 4 * lg + r_;                                           \
        int jj_ = row_ >> 1;                                                       \
        float vq_ = ACC[n_][r_] + bias_;                                           \
        float aw_ = ubf(lds[O_LG + ((DY) * 128 + row_) * 8 + nt_]);                \
        float vv_ = ubf(lds[O_V + jj_ * 128 + (o_ ^ ((jj_ & 7) << 3))]);           \
        float wg_ = 1.f / (1.f + __expf(-(smf[jj_ * 8 + nt_] + cmv_)));            \
        float xc_ = (1.f - wg_) * aw_ * vv_ * 4.f + wg_ * vq_;                     \
        lds[O_XA + row_ * 128 + (o_ ^ ((row_ & 7) << 3))] = (unsigned short)bf16r(xc_); \
      } } } while (0)

// ---------------- kernel 3: fused main ----------------
__global__ __launch_bounds__(512, 4) void pafm_v6(
    const float* __restrict__ x_l,  const float* __restrict__ x_r,
    const float* __restrict__ x_lh, const float* __restrict__ x_rh,
    const float* __restrict__ bq,   const float* __restrict__ bqv,
    const float* __restrict__ bk,   const float* __restrict__ bv,
    const float* __restrict__ bp,
    const float* __restrict__ ln_g, const float* __restrict__ ln_b,
    const float* __restrict__ d_ln1_g, const float* __restrict__ d_ln1_b,
    const float* __restrict__ d_wsv,
    const float* __restrict__ ws_cm,
    const unsigned short* __restrict__ wsp,
    float* __restrict__ out) {

    __shared__ unsigned short lds[LDS_U16];
    float* smf = (float*)&lds[O_SM];

    int bid = blockIdx.x;                 // s(1)|b(2)|i0(7)|jb(1)
    int s  = bid >> 10;
    int b  = (bid >> 8) & 3;
    int i0 = (bid >> 1) & 127;
    int j0 = (bid & 1) * 64;

    int t = threadIdx.x, w = t >> 6, l = t & 63, lm = l & 15, lg = l >> 4;

    const float* xlow  = s ? x_r  : x_l;
    const float* xhigh = s ? x_rh : x_lh;
    const float* cmp   = ws_cm + (s * 4 + b) * 128;

    float gw = d_ln1_g[lm] * d_wsv[lm];
    float S1 = gw, S2 = d_ln1_b[lm] * d_wsv[lm];
    #pragma unroll
    for (int d = 1; d < 16; d <<= 1) { S1 += __shfl_xor(S1, d, 64); S2 += __shfl_xor(S2, d, 64); }

    const float* lowb = xlow + ((size_t)(b * 256) * 128 + i0) * 128 + j0;
    const float* hbase = xhigh + ((size_t)(b * 128) * 256 + 2 * i0) * 256 + 2 * j0;

    smf[t & 511] = 0.f;

    // ---- stage x_low; K+V GEMMs (B-frags from global pool), no inner barriers ----
    stageA16<64, 256>(lowb, 16384, lds, O_XA, t);
    __syncthreads();
    {
        int nt = w >> 2, mt = w & 3;
        #pragma unroll
        for (int q = 0; q < 4; ++q) {
            f32x4 aK = (f32x4){0.f,0.f,0.f,0.f}, aV = (f32x4){0.f,0.f,0.f,0.f};
            #pragma unroll
            for (int kc = 0; kc < 8; ++kc) {
                short8 af = frag(lds, O_XA, 16 * mt + lm, kc * 32 + lg * 8, 256);
                aK = __builtin_amdgcn_mfma_f32_16x16x32_bf16(
                        af, wfrag(wsp + q * 8192, 16 * nt + lm, kc * 32 + lg * 8, 256), aK, 0, 0, 0);
                aV = __builtin_amdgcn_mfma_f32_16x16x32_bf16(
                        af, wfrag(wsp + 32768 + q * 8192, 16 * nt + lm, kc * 32 + lg * 8, 256), aV, 0, 0, 0);
            }
            int o = q * 32 + 16 * nt + lm;
            float bbk = bk[o], bbv = bv[o];
            #pragma unroll
            for (int r = 0; r < 4; ++r) {
                int tok = 16 * mt + 4 * lg + r;
                lds[O_K + tok * 128 + (o ^ ((tok & 7) << 3))] = (unsigned short)bf16r(aK[r] + bbk);
                lds[O_V + tok * 128 + (o ^ ((tok & 7) << 3))] = (unsigned short)bf16r(aV[r] + bbv);
            }
        }
    }

    // ---- pass 1: Q GEMM + logits + DANE ----
    #pragma unroll 1
    for (int dy = 0; dy < 2; ++dy) {
        __syncthreads();
        stageA16<128, 128>(hbase + dy * 256, 65536, lds, O_XA, t);
        __syncthreads();
        f32x4 qA[4], qB[4];
        ZERO4(qA); ZERO4(qB);
        #pragma unroll
        for (int kc = 0; kc < 4; ++kc) {
            short8 af = frag(lds, O_XA, 16 * w + lm, kc * 32 + lg * 8, 128);
            #pragma unroll
            for (int n = 0; n < 4; ++n)
                qA[n] = __builtin_amdgcn_mfma_f32_16x16x32_bf16(
                          af, wfrag(wsp + 65536, 16 * n + lm, kc * 32 + lg * 8, 128), qA[n], 0, 0, 0);
            #pragma unroll
            for (int n = 0; n < 4; ++n)
                qB[n] = __builtin_amdgcn_mfma_f32_16x16x32_bf16(
                          af, wfrag(wsp + 65536 + 8192, 16 * n + lm, kc * 32 + lg * 8, 128), qB[n], 0, 0, 0);
        }
        CONSUME(qA, dy, 0);
        CONSUME(qB, dy, 1);
    }
    __syncthreads();

    // ---- softmax over 4 px + finalize sm ----
    {
        int jj = t >> 3, h = t & 7;
        int r00 = (2 * jj) * 8 + h,       r01 = (2 * jj + 1) * 8 + h;
        int r10 = (128 + 2 * jj) * 8 + h, r11 = (128 + 2 * jj + 1) * 8 + h;
        float l00 = ubf(lds[O_LG + r00]), l01 = ubf(lds[O_LG + r01]);
        float l10 = ubf(lds[O_LG + r10]), l11 = ubf(lds[O_LG + r11]);
        float mx = fmaxf(fmaxf(l00, l01), fmaxf(l10, l11));
        float e00 = __expf(l00 - mx), e01 = __expf(l01 - mx);
        float e10 = __expf(l10 - mx), e11 = __expf(l11 - mx);
        float inv = 1.f / (e00 + e01 + e10 + e11);
        lds[O_LG + r00] = (unsigned short)bf16r(e00 * inv);
        lds[O_LG + r01] = (unsigned short)bf16r(e01 * inv);
        lds[O_LG + r10] = (unsigned short)bf16r(e10 * inv);
        lds[O_LG + r11] = (unsigned short)bf16r(e11 * inv);
        smf[jj * 8 + h] *= 0.25f;
    }
    __syncthreads();

    // ---- pass 2 per dy: VQ -> combine -> P -> LN -> store ----
    #pragma unroll 1
    for (int dy = 0; dy < 2; ++dy) {
        stageA16<128, 128>(hbase + dy * 256, 65536, lds, O_XA, t);
        __syncthreads();
        f32x4 vqA[4], vqB[4];
        ZERO4(vqA); ZERO4(vqB);
        #pragma unroll
        for (int kc = 0; kc < 4; ++kc) {
            short8 af = frag(lds, O_XA, 16 * w + lm, kc * 32 + lg * 8, 128);
            #pragma unroll
            for (int n = 0; n < 4; ++n)
                vqA[n] = __builtin_amdgcn_mfma_f32_16x16x32_bf16(
                           af, wfrag(wsp + 81920, 16 * n + lm, kc * 32 + lg * 8, 128), vqA[n], 0, 0, 0);
            #pragma unroll
            for (int n = 0; n < 4; ++n)
                vqB[n] = __builtin_amdgcn_mfma_f32_16x16x32_bf16(
                           af, wfrag(wsp + 81920 + 8192, 16 * n + lm, kc * 32 + lg * 8, 128), vqB[n], 0, 0, 0);
        }
        __syncthreads();                 // VQ reads of XA done
        COMBINE(vqA, dy, 0);
        COMBINE(vqB, dy, 1);
        __syncthreads();                 // xc visible

        f32x4 pA[4], pB[4];
        ZERO4(pA); ZERO4(pB);
        #pragma unroll
        for (int kc = 0; kc < 4; ++kc) {
            short8 af = frag(lds, O_XA, 16 * w + lm, kc * 32 + lg * 8, 128);
            #pragma unroll
            for (int n = 0; n < 4; ++n)
                pA[n] = __builtin_amdgcn_mfma_f32_16x16x32_bf16(
                          af, wfrag(wsp + 98304, 16 * n + lm, kc * 32 + lg * 8, 128), pA[n], 0, 0, 0);
            #pragma unroll
            for (int n = 0; n < 4; ++n)
                pB[n] = __builtin_amdgcn_mfma_f32_16x16x32_bf16(
                          af, wfrag(wsp + 98304 + 8192, 16 * n + lm, kc * 32 + lg * 8, 128), pB[n], 0, 0, 0);
        }
        __syncthreads();                 // P reads of XA done

        float mean_[4], rstd_[4];
        #pragma unroll
        for (int r = 0; r < 4; ++r) {
            float ps = 0.f, pq = 0.f;
            #pragma unroll
            for (int n = 0; n < 4; ++n) {
                float y0 = pA[n][r] + bp[16 * n + lm];
                float y1 = pB[n][r] + bp[64 + 16 * n + lm];
                ps += y0 + y1;
                pq = fmaf(y0, y0, pq); pq = fmaf(y1, y1, pq);
            }
            #pragma unroll
            for (int d = 1; d < 16; d <<= 1) { ps += __shfl_xor(ps, d, 64); pq += __shfl_xor(pq, d, 64); }
            float mn = ps * (1.f / 128.f);
            mean_[r] = mn;
            rstd_[r] = rsqrtf(pq * (1.f / 128.f) - mn * mn + 1e-5f);
        }
        // yn -> XA, u32-pair-swizzled: u16 col = ((o>>1) ^ (row&31))*2 + (o&1)
        #pragma unroll
        for (int n = 0; n < 4; ++n) {
            int oA = 16 * n + lm, oB = 64 + 16 * n + lm;
            float gA = ln_g[oA], bA = ln_b[oA], biA = bp[oA];
            float gB = ln_g[oB], bB = ln_b[oB], biB = bp[oB];
            #pragma unroll
            for (int r = 0; r < 4; ++r) {
                int row = 16 * w + 4 * lg + r;
                float ynA = (pA[n][r] + biA - mean_[r]) * rstd_[r] * gA + bA;
                float ynB = (pB[n][r] + biB - mean_[r]) * rstd_[r] * gB + bB;
                lds[O_XA + row * 128 + ((((oA >> 1) ^ (row & 31)) << 1) | (oA & 1))] = (unsigned short)bf16r(ynA);
                lds[O_XA + row * 128 + ((((oB >> 1) ^ (row & 31)) << 1) | (oB & 1))] = (unsigned short)bf16r(ynB);
            }
        }
        __syncthreads();
        // store: u32 yn reads (conflict-free), residual from global (L2-hot)
        {
            const float* rb = hbase + dy * 256;
            float* ob = out + (size_t)s * 33554432
                      + ((size_t)(b * 128)) * 65536 + (size_t)(2 * i0 + dy) * 256 + 2 * j0;
            int ph = t & 127, cq = t >> 7;
            #pragma unroll
            for (int it = 0; it < 16; ++it) {
                int c4 = it * 4 + cq;
                unsigned uv = *(const unsigned*)&lds[O_XA + ph * 128 + ((c4 ^ (ph & 31)) << 1)];
                size_t off0 = (size_t)(2 * c4) * 65536 + ph;
                size_t off1 = off0 + 65536;
                ob[off0] = rb[off0] + ubf((unsigned short)(uv & 0xFFFF));
                ob[off1] = rb[off1] + ubf((unsigned short)(uv >> 16));
            }
        }
        if (dy == 0) __syncthreads();
    }
}

extern "C" void kernel_launch(void* const* d_in, const int* in_sizes, int n_in,
                              void* d_out, int out_size, void* d_ws, size_t ws_size,
                              hipStream_t stream) {
    const float* x_l   = (const float*)d_in[0];
    const float* x_r   = (const float*)d_in[1];
    const float* x_lh  = (const float*)d_in[2];
    const float* x_rh  = (const float*)d_in[3];
    const float* Wq    = (const float*)d_in[4];
    const float* bq    = (const float*)d_in[5];
    const float* Wqv   = (const float*)d_in[6];
    const float* bqv   = (const float*)d_in[7];
    const float* Wk    = (const float*)d_in[8];
    const float* bk    = (const float*)d_in[9];
    const float* Wv    = (const float*)d_in[10];
    const float* bv    = (const float*)d_in[11];
    const float* Wp    = (const float*)d_in[12];
    const float* bp    = (const float*)d_in[13];
    const float* ln_g  = (const float*)d_in[14];
    const float* ln_b  = (const float*)d_in[15];
    const float* dln1g = (const float*)d_in[16];
    const float* dln1b = (const float*)d_in[17];
    const float* d_wsv = (const float*)d_in[18];
    const float* d_w1  = (const float*)d_in[19];
    const float* dln2g = (const float*)d_in[20];
    const float* dln2b = (const float*)d_in[21];
    const float* d_w2  = (const float*)d_in[22];

    float* out = (float*)d_out;
    float* ws_mean = (float*)d_ws;                                 // 2048 f
    float* ws_cm   = ws_mean + 2048;                               // 1024 f
    unsigned short* wsp = (unsigned short*)((char*)d_ws + 16384);  // 224 KB bf16 pool

    mean_kernel<<<2048, 256, 0, stream>>>(x_l, x_r, ws_mean);
    wprep<<<112, 256, 0, stream>>>(Wq, Wqv, Wk, Wv, Wp, wsp);
    cm_kernel<<<8, 128, 0, stream>>>(ws_mean, ws_cm, Wk, bk, d_w1, dln2g, dln2b, d_w2);
    pafm_v6<<<2048, 512, 0, stream>>>(x_l, x_r, x_lh, x_rh,
                                      bq, bqv, bk, bv, bp, ln_g, ln_b,
                                      dln1g, dln1b, d_wsv, ws_cm, wsp, out);
}

// Round 13
// 1610.697 us; speedup vs baseline: 1.2725x; 1.2725x over previous
//
#include <hip/hip_runtime.h>
#include <hip/hip_bf16.h>
#include <math.h>

// PAFM fused v7: v6 with launch_bounds(512,2) — restores 128-VGPR budget (v6's
// (512,4) forced 64 VGPR -> scratch spill, WRITE 2.5GB). Weights as per-lane
// global fragments from pre-swizzled bf16 pool; 70KB LDS -> 2 blocks/CU.
// Inputs fp32 dict order; output fp32. Grid 2048 x 512 thr (block = 64 patches).

typedef short short8 __attribute__((ext_vector_type(8)));
typedef float f32x4 __attribute__((ext_vector_type(4)));
typedef unsigned uint4v __attribute__((ext_vector_type(4)));

__device__ __forceinline__ unsigned bf16r(float x) {
    unsigned u = __float_as_uint(x);
    return (u + 0x7FFFu + ((u >> 16) & 1u)) >> 16;
}
__device__ __forceinline__ unsigned pack2(float a, float b) {
    return bf16r(a) | (bf16r(b) << 16);
}
__device__ __forceinline__ float ubf(unsigned short h) {
    return __uint_as_float(((unsigned)h) << 16);
}

// ---------------- kernel 1: per-(side,b,channel) spatial mean of x_low ----------------
__global__ __launch_bounds__(256) void mean_kernel(const float* __restrict__ x_l,
                                                   const float* __restrict__ x_r,
                                                   float* __restrict__ ws_mean) {
    int bid = blockIdx.x;
    const float* src = (bid >= 1024) ? x_r : x_l;
    const float* p = src + (size_t)(bid & 1023) * 16384;
    int t = threadIdx.x;
    float acc = 0.f;
    #pragma unroll 4
    for (int i = t; i < 16384; i += 256) acc += p[i];
    #pragma unroll
    for (int off = 32; off > 0; off >>= 1) acc += __shfl_down(acc, off, 64);
    __shared__ float red[4];
    if ((t & 63) == 0) red[t >> 6] = acc;
    __syncthreads();
    if (t == 0) ws_mean[bid] = (red[0] + red[1] + red[2] + red[3]) * (1.f / 16384.f);
}

// ---------------- kernel 2: channel gate cm[side][b][128] ----------------
__global__ __launch_bounds__(128) void cm_kernel(const float* __restrict__ ws_mean,
                                                 float* __restrict__ ws_cm,
                                                 const float* __restrict__ Wk,
                                                 const float* __restrict__ bk,
                                                 const float* __restrict__ d_w1,
                                                 const float* __restrict__ d_ln2_g,
                                                 const float* __restrict__ d_ln2_b,
                                                 const float* __restrict__ d_w2) {
    int sb = blockIdx.x;
    __shared__ float km[128];
    int o = threadIdx.x;
    const float* mu = ws_mean + sb * 256;
    float acc = bk[o];
    for (int c = 0; c < 256; ++c) acc = fmaf(Wk[o * 256 + c], mu[c], acc);
    km[o] = acc;
    __syncthreads();
    int h = o >> 4, d = o & 15;
    float t1[8];
    #pragma unroll
    for (int r = 0; r < 8; ++r) {
        float a = 0.f;
        #pragma unroll
        for (int dd = 0; dd < 16; ++dd) a = fmaf(d_w1[r * 16 + dd], km[h * 16 + dd], a);
        t1[r] = a / (1.f + expf(-a));
    }
    float m = 0.f;
    #pragma unroll
    for (int r = 0; r < 8; ++r) m += t1[r];
    m *= 0.125f;
    float v = 0.f;
    #pragma unroll
    for (int r = 0; r < 8; ++r) { float df = t1[r] - m; v = fmaf(df, df, v); }
    float rstd = rsqrtf(v * 0.125f + 1e-5f);
    float cmv = 0.f;
    #pragma unroll
    for (int r = 0; r < 8; ++r)
        cmv = fmaf((t1[r] - m) * rstd * d_ln2_g[r] + d_ln2_b[r], d_w2[d * 8 + r], cmv);
    ws_cm[sb * 128 + o] = cmv;
}

// ---------------- kernel 2b: weights -> bf16 pre-swizzled pool in ws ----------------
// pool (u16): WK=0 [4][32][256]; WV=32768; WQ=65536 [2][64][128]; WQV=81920; WP=98304
__global__ __launch_bounds__(256) void wprep(const float* __restrict__ Wq,
                                             const float* __restrict__ Wqv,
                                             const float* __restrict__ Wk,
                                             const float* __restrict__ Wv,
                                             const float* __restrict__ Wp,
                                             unsigned short* __restrict__ wsp) {
    int bid = blockIdx.x, t = threadIdx.x;
    if (bid < 64) {
        const float* src = (bid < 32) ? Wk : Wv;
        unsigned short* dst = wsp + ((bid < 32) ? 0 : 32768);
        int base = (bid & 31) * 1024;
        #pragma unroll
        for (int i = 0; i < 4; ++i) {
            int el = base + t + 256 * i;
            int q = el >> 13, rem = el & 8191, op = rem >> 8, col = rem & 255;
            dst[q * 8192 + op * 256 + (col ^ ((op & 7) << 3))] =
                (unsigned short)bf16r(src[(q * 32 + op) * 256 + col]);
        }
    } else {
        int g = (bid - 64) >> 4;
        const float* src = (g == 0) ? Wq : (g == 1) ? Wqv : Wp;
        unsigned short* dst = wsp + 65536 + g * 16384;
        int base = ((bid - 64) & 15) * 1024;
        #pragma unroll
        for (int i = 0; i < 4; ++i) {
            int el = base + t + 256 * i;
            int hf = el >> 13, rem = el & 8191, op = rem >> 7, col = rem & 127;
            dst[hf * 8192 + op * 128 + (col ^ ((op & 7) << 3))] =
                (unsigned short)bf16r(src[(hf * 64 + op) * 128 + col]);
        }
    }
}

// LDS offsets (u16)
#define O_XA 0       // 16384: x_low 64x256 / x_high 128x128 / xc / yn
#define O_K  16384   // 8192: [64][128]
#define O_V  24576   // 8192
#define O_LG 32768   // 2048: [256 rows][8 heads]
#define O_SM 34816   // 1024 u16 = 512 f32
#define LDS_U16 35840 // 70 KB

__device__ __forceinline__ short8 frag(const unsigned short* lds, int off, int row, int k, int C2) {
    return *(const short8*)&lds[off + row * C2 + (k ^ ((row & 7) << 3))];
}
__device__ __forceinline__ short8 wfrag(const unsigned short* __restrict__ p, int row, int k, int C2) {
    return *(const short8*)&p[row * C2 + (k ^ ((row & 7) << 3))];
}

// stage fp32 tile -> bf16 LDS, 16B/lane writes, coalesced global reads
template<int R, int C2>
__device__ __forceinline__ void stageA16(const float* __restrict__ g, size_t cstride,
                                         unsigned short* lds, int off, int t) {
    #pragma unroll
    for (int it = 0; it < (R * (C2 / 8)) / 512; ++it) {
        int idx = t + it * 512;
        int rr = idx & (R - 1);
        int bc = idx / R;
        float v0 = g[(size_t)(8 * bc + 0) * cstride + rr];
        float v1 = g[(size_t)(8 * bc + 1) * cstride + rr];
        float v2 = g[(size_t)(8 * bc + 2) * cstride + rr];
        float v3 = g[(size_t)(8 * bc + 3) * cstride + rr];
        float v4 = g[(size_t)(8 * bc + 4) * cstride + rr];
        float v5 = g[(size_t)(8 * bc + 5) * cstride + rr];
        float v6 = g[(size_t)(8 * bc + 6) * cstride + rr];
        float v7 = g[(size_t)(8 * bc + 7) * cstride + rr];
        uint4v u = {pack2(v0, v1), pack2(v2, v3), pack2(v4, v5), pack2(v6, v7)};
        *(uint4v*)&lds[off + rr * C2 + ((bc ^ (rr & 7)) << 3)] = u;
    }
}

#define ZERO4(A) do { _Pragma("unroll") for (int z_ = 0; z_ < 4; ++z_) A[z_] = (f32x4){0.f,0.f,0.f,0.f}; } while (0)

#define CONSUME(ACC, DY, NH) do {                                                  \
    _Pragma("unroll")                                                              \
    for (int n_ = 0; n_ < 4; ++n_) {                                               \
      int nt_ = 4 * (NH) + n_;                                                     \
      int o_ = 16 * nt_ + lm;                                                      \
      float bias_ = bq[o_];                                                        \
      float sd01_ = 0.f, sd23_ = 0.f;                                              \
      _Pragma("unroll")                                                            \
      for (int r_ = 0; r_ < 4; ++r_) {                                             \
        int row_ = 16 * w + 4 * lg + r_;                                           \
        int tok_ = row_ >> 1;                                                      \
        float q_ = ACC[n_][r_] + bias_;                                            \
        float kv_ = ubf(lds[O_K + tok_ * 128 + (o_ ^ ((tok_ & 7) << 3))]);         \
        float t0_ = q_, t1_ = q_ * q_, t2_ = q_ * gw, t3_ = q_ * kv_;              \
        _Pragma("unroll")                                                          \
        for (int d_ = 1; d_ < 16; d_ <<= 1) {                                      \
          t0_ += __shfl_xor(t0_, d_, 64); t1_ += __shfl_xor(t1_, d_, 64);          \
          t2_ += __shfl_xor(t2_, d_, 64); t3_ += __shfl_xor(t3_, d_, 64);          \
        }                                                                          \
        float mn_ = t0_ * 0.0625f;                                                 \
        float rs_ = rsqrtf(t1_ * 0.0625f - mn_ * mn_ + 1e-5f);                     \
        float sdt_ = rs_ * (t2_ - mn_ * S1) + S2;                                  \
        if (r_ < 2) sd01_ += sdt_; else sd23_ += sdt_;                             \
        if (lm == r_) lds[O_LG + ((DY) * 128 + row_) * 8 + nt_] = (unsigned short)bf16r(t3_ * 0.25f); \
      }                                                                            \
      if (lm == 0) smf[(8 * w + 2 * lg) * 8 + nt_]     += sd01_;                   \
      if (lm == 1) smf[(8 * w + 2 * lg + 1) * 8 + nt_] += sd23_;                   \
    } } while (0)

#define COMBINE(ACC, DY, NH) do {                                                  \
    _Pragma("unroll")                                                              \
    for (int n_ = 0; n_ < 4; ++n_) {                                               \
      int nt_ = 4 * (NH) + n_;                                                     \
      int o_ = 16 * nt_ + lm;                                                      \
      float bias_ = bqv[o_];                                                       \
      float cmv_ = cmp[o_];                                                        \
      _Pragma("unroll")                                                            \
      for (int r_ = 0; r_ < 4; ++r_) {                                             \
        int row_ = 16 * w + 4 * lg + r_;                                           \
        int jj_ = row_ >> 1;                                                       \
        float vq_ = ACC[n_][r_] + bias_;                                           \
        float aw_ = ubf(lds[O_LG + ((DY) * 128 + row_) * 8 + nt_]);                \
        float vv_ = ubf(lds[O_V + jj_ * 128 + (o_ ^ ((jj_ & 7) << 3))]);           \
        float wg_ = 1.f / (1.f + __expf(-(smf[jj_ * 8 + nt_] + cmv_)));            \
        float xc_ = (1.f - wg_) * aw_ * vv_ * 4.f + wg_ * vq_;                     \
        lds[O_XA + row_ * 128 + (o_ ^ ((row_ & 7) << 3))] = (unsigned short)bf16r(xc_); \
      } } } while (0)

// ---------------- kernel 3: fused main ----------------
__global__ __launch_bounds__(512, 2) void pafm_v7(
    const float* __restrict__ x_l,  const float* __restrict__ x_r,
    const float* __restrict__ x_lh, const float* __restrict__ x_rh,
    const float* __restrict__ bq,   const float* __restrict__ bqv,
    const float* __restrict__ bk,   const float* __restrict__ bv,
    const float* __restrict__ bp,
    const float* __restrict__ ln_g, const float* __restrict__ ln_b,
    const float* __restrict__ d_ln1_g, const float* __restrict__ d_ln1_b,
    const float* __restrict__ d_wsv,
    const float* __restrict__ ws_cm,
    const unsigned short* __restrict__ wsp,
    float* __restrict__ out) {

    __shared__ unsigned short lds[LDS_U16];
    float* smf = (float*)&lds[O_SM];

    int bid = blockIdx.x;                 // s(1)|b(2)|i0(7)|jb(1)
    int s  = bid >> 10;
    int b  = (bid >> 8) & 3;
    int i0 = (bid >> 1) & 127;
    int j0 = (bid & 1) * 64;

    int t = threadIdx.x, w = t >> 6, l = t & 63, lm = l & 15, lg = l >> 4;

    const float* xlow  = s ? x_r  : x_l;
    const float* xhigh = s ? x_rh : x_lh;
    const float* cmp   = ws_cm + (s * 4 + b) * 128;

    float gw = d_ln1_g[lm] * d_wsv[lm];
    float S1 = gw, S2 = d_ln1_b[lm] * d_wsv[lm];
    #pragma unroll
    for (int d = 1; d < 16; d <<= 1) { S1 += __shfl_xor(S1, d, 64); S2 += __shfl_xor(S2, d, 64); }

    const float* lowb = xlow + ((size_t)(b * 256) * 128 + i0) * 128 + j0;
    const float* hbase = xhigh + ((size_t)(b * 128) * 256 + 2 * i0) * 256 + 2 * j0;

    smf[t & 511] = 0.f;

    // ---- stage x_low; K+V GEMMs (B-frags from global pool), no inner barriers ----
    stageA16<64, 256>(lowb, 16384, lds, O_XA, t);
    __syncthreads();
    {
        int nt = w >> 2, mt = w & 3;
        #pragma unroll
        for (int q = 0; q < 4; ++q) {
            f32x4 aK = (f32x4){0.f,0.f,0.f,0.f}, aV = (f32x4){0.f,0.f,0.f,0.f};
            #pragma unroll
            for (int kc = 0; kc < 8; ++kc) {
                short8 af = frag(lds, O_XA, 16 * mt + lm, kc * 32 + lg * 8, 256);
                aK = __builtin_amdgcn_mfma_f32_16x16x32_bf16(
                        af, wfrag(wsp + q * 8192, 16 * nt + lm, kc * 32 + lg * 8, 256), aK, 0, 0, 0);
                aV = __builtin_amdgcn_mfma_f32_16x16x32_bf16(
                        af, wfrag(wsp + 32768 + q * 8192, 16 * nt + lm, kc * 32 + lg * 8, 256), aV, 0, 0, 0);
            }
            int o = q * 32 + 16 * nt + lm;
            float bbk = bk[o], bbv = bv[o];
            #pragma unroll
            for (int r = 0; r < 4; ++r) {
                int tok = 16 * mt + 4 * lg + r;
                lds[O_K + tok * 128 + (o ^ ((tok & 7) << 3))] = (unsigned short)bf16r(aK[r] + bbk);
                lds[O_V + tok * 128 + (o ^ ((tok & 7) << 3))] = (unsigned short)bf16r(aV[r] + bbv);
            }
        }
    }

    // ---- pass 1: Q GEMM + logits + DANE ----
    #pragma unroll 1
    for (int dy = 0; dy < 2; ++dy) {
        __syncthreads();
        stageA16<128, 128>(hbase + dy * 256, 65536, lds, O_XA, t);
        __syncthreads();
        f32x4 qA[4], qB[4];
        ZERO4(qA); ZERO4(qB);
        #pragma unroll
        for (int kc = 0; kc < 4; ++kc) {
            short8 af = frag(lds, O_XA, 16 * w + lm, kc * 32 + lg * 8, 128);
            #pragma unroll
            for (int n = 0; n < 4; ++n)
                qA[n] = __builtin_amdgcn_mfma_f32_16x16x32_bf16(
                          af, wfrag(wsp + 65536, 16 * n + lm, kc * 32 + lg * 8, 128), qA[n], 0, 0, 0);
            #pragma unroll
            for (int n = 0; n < 4; ++n)
                qB[n] = __builtin_amdgcn_mfma_f32_16x16x32_bf16(
                          af, wfrag(wsp + 65536 + 8192, 16 * n + lm, kc * 32 + lg * 8, 128), qB[n], 0, 0, 0);
        }
        CONSUME(qA, dy, 0);
        CONSUME(qB, dy, 1);
    }
    __syncthreads();

    // ---- softmax over 4 px + finalize sm ----
    {
        int jj = t >> 3, h = t & 7;
        int r00 = (2 * jj) * 8 + h,       r01 = (2 * jj + 1) * 8 + h;
        int r10 = (128 + 2 * jj) * 8 + h, r11 = (128 + 2 * jj + 1) * 8 + h;
        float l00 = ubf(lds[O_LG + r00]), l01 = ubf(lds[O_LG + r01]);
        float l10 = ubf(lds[O_LG + r10]), l11 = ubf(lds[O_LG + r11]);
        float mx = fmaxf(fmaxf(l00, l01), fmaxf(l10, l11));
        float e00 = __expf(l00 - mx), e01 = __expf(l01 - mx);
        float e10 = __expf(l10 - mx), e11 = __expf(l11 - mx);
        float inv = 1.f / (e00 + e01 + e10 + e11);
        lds[O_LG + r00] = (unsigned short)bf16r(e00 * inv);
        lds[O_LG + r01] = (unsigned short)bf16r(e01 * inv);
        lds[O_LG + r10] = (unsigned short)bf16r(e10 * inv);
        lds[O_LG + r11] = (unsigned short)bf16r(e11 * inv);
        smf[jj * 8 + h] *= 0.25f;
    }
    __syncthreads();

    // ---- pass 2 per dy: VQ -> combine -> P -> LN -> store ----
    #pragma unroll 1
    for (int dy = 0; dy < 2; ++dy) {
        stageA16<128, 128>(hbase + dy * 256, 65536, lds, O_XA, t);
        __syncthreads();
        f32x4 vqA[4], vqB[4];
        ZERO4(vqA); ZERO4(vqB);
        #pragma unroll
        for (int kc = 0; kc < 4; ++kc) {
            short8 af = frag(lds, O_XA, 16 * w + lm, kc * 32 + lg * 8, 128);
            #pragma unroll
            for (int n = 0; n < 4; ++n)
                vqA[n] = __builtin_amdgcn_mfma_f32_16x16x32_bf16(
                           af, wfrag(wsp + 81920, 16 * n + lm, kc * 32 + lg * 8, 128), vqA[n], 0, 0, 0);
            #pragma unroll
            for (int n = 0; n < 4; ++n)
                vqB[n] = __builtin_amdgcn_mfma_f32_16x16x32_bf16(
                           af, wfrag(wsp + 81920 + 8192, 16 * n + lm, kc * 32 + lg * 8, 128), vqB[n], 0, 0, 0);
        }
        __syncthreads();                 // VQ reads of XA done
        COMBINE(vqA, dy, 0);
        COMBINE(vqB, dy, 1);
        __syncthreads();                 // xc visible

        f32x4 pA[4], pB[4];
        ZERO4(pA); ZERO4(pB);
        #pragma unroll
        for (int kc = 0; kc < 4; ++kc) {
            short8 af = frag(lds, O_XA, 16 * w + lm, kc * 32 + lg * 8, 128);
            #pragma unroll
            for (int n = 0; n < 4; ++n)
                pA[n] = __builtin_amdgcn_mfma_f32_16x16x32_bf16(
                          af, wfrag(wsp + 98304, 16 * n + lm, kc * 32 + lg * 8, 128), pA[n], 0, 0, 0);
            #pragma unroll
            for (int n = 0; n < 4; ++n)
                pB[n] = __builtin_amdgcn_mfma_f32_16x16x32_bf16(
                          af, wfrag(wsp + 98304 + 8192, 16 * n + lm, kc * 32 + lg * 8, 128), pB[n], 0, 0, 0);
        }
        __syncthreads();                 // P reads of XA done

        float mean_[4], rstd_[4];
        #pragma unroll
        for (int r = 0; r < 4; ++r) {
            float ps = 0.f, pq = 0.f;
            #pragma unroll
            for (int n = 0; n < 4; ++n) {
                float y0 = pA[n][r] + bp[16 * n + lm];
                float y1 = pB[n][r] + bp[64 + 16 * n + lm];
                ps += y0 + y1;
                pq = fmaf(y0, y0, pq); pq = fmaf(y1, y1, pq);
            }
            #pragma unroll
            for (int d = 1; d < 16; d <<= 1) { ps += __shfl_xor(ps, d, 64); pq += __shfl_xor(pq, d, 64); }
            float mn = ps * (1.f / 128.f);
            mean_[r] = mn;
            rstd_[r] = rsqrtf(pq * (1.f / 128.f) - mn * mn + 1e-5f);
        }
        // yn -> XA, u32-pair-swizzled: u16 col = ((o>>1) ^ (row&31))*2 + (o&1)
        #pragma unroll
        for (int n = 0; n < 4; ++n) {
            int oA = 16 * n + lm, oB = 64 + 16 * n + lm;
            float gA = ln_g[oA], bA = ln_b[oA], biA = bp[oA];
            float gB = ln_g[oB], bB = ln_b[oB], biB = bp[oB];
            #pragma unroll
            for (int r = 0; r < 4; ++r) {
                int row = 16 * w + 4 * lg + r;
                float ynA = (pA[n][r] + biA - mean_[r]) * rstd_[r] * gA + bA;
                float ynB = (pB[n][r] + biB - mean_[r]) * rstd_[r] * gB + bB;
                lds[O_XA + row * 128 + ((((oA >> 1) ^ (row & 31)) << 1) | (oA & 1))] = (unsigned short)bf16r(ynA);
                lds[O_XA + row * 128 + ((((oB >> 1) ^ (row & 31)) << 1) | (oB & 1))] = (unsigned short)bf16r(ynB);
            }
        }
        __syncthreads();
        // store: u32 yn reads (conflict-free), residual from global (L2-hot)
        {
            const float* rb = hbase + dy * 256;
            float* ob = out + (size_t)s * 33554432
                      + ((size_t)(b * 128)) * 65536 + (size_t)(2 * i0 + dy) * 256 + 2 * j0;
            int ph = t & 127, cq = t >> 7;
            #pragma unroll
            for (int it = 0; it < 16; ++it) {
                int c4 = it * 4 + cq;
                unsigned uv = *(const unsigned*)&lds[O_XA + ph * 128 + ((c4 ^ (ph & 31)) << 1)];
                size_t off0 = (size_t)(2 * c4) * 65536 + ph;
                size_t off1 = off0 + 65536;
                ob[off0] = rb[off0] + ubf((unsigned short)(uv & 0xFFFF));
                ob[off1] = rb[off1] + ubf((unsigned short)(uv >> 16));
            }
        }
        if (dy == 0) __syncthreads();
    }
}

extern "C" void kernel_launch(void* const* d_in, const int* in_sizes, int n_in,
                              void* d_out, int out_size, void* d_ws, size_t ws_size,
                              hipStream_t stream) {
    const float* x_l   = (const float*)d_in[0];
    const float* x_r   = (const float*)d_in[1];
    const float* x_lh  = (const float*)d_in[2];
    const float* x_rh  = (const float*)d_in[3];
    const float* Wq    = (const float*)d_in[4];
    const float* bq    = (const float*)d_in[5];
    const float* Wqv   = (const float*)d_in[6];
    const float* bqv   = (const float*)d_in[7];
    const float* Wk    = (const float*)d_in[8];
    const float* bk    = (const float*)d_in[9];
    const float* Wv    = (const float*)d_in[10];
    const float* bv    = (const float*)d_in[11];
    const float* Wp    = (const float*)d_in[12];
    const float* bp    = (const float*)d_in[13];
    const float* ln_g  = (const float*)d_in[14];
    const float* ln_b  = (const float*)d_in[15];
    const float* dln1g = (const float*)d_in[16];
    const float* dln1b = (const float*)d_in[17];
    const float* d_wsv = (const float*)d_in[18];
    const float* d_w1  = (const float*)d_in[19];
    const float* dln2g = (const float*)d_in[20];
    const float* dln2b = (const float*)d_in[21];
    const float* d_w2  = (const float*)d_in[22];

    float* out = (float*)d_out;
    float* ws_mean = (float*)d_ws;                                 // 2048 f
    float* ws_cm   = ws_mean + 2048;                               // 1024 f
    unsigned short* wsp = (unsigned short*)((char*)d_ws + 16384);  // 224 KB bf16 pool

    mean_kernel<<<2048, 256, 0, stream>>>(x_l, x_r, ws_mean);
    wprep<<<112, 256, 0, stream>>>(Wq, Wqv, Wk, Wv, Wp, wsp);
    cm_kernel<<<8, 128, 0, stream>>>(ws_mean, ws_cm, Wk, bk, d_w1, dln2g, dln2b, d_w2);
    pafm_v7<<<2048, 512, 0, stream>>>(x_l, x_r, x_lh, x_rh,
                                      bq, bqv, bk, bv, bp, ln_g, ln_b,
                                      dln1g, dln1b, d_wsv, ws_cm, wsp, out);
}

// Round 14
// 803.619 us; speedup vs baseline: 2.5504x; 2.0043x over previous
//
#include <hip/hip_runtime.h>
#include <hip/hip_bf16.h>
#include <math.h>

// PAFM fused v8: staged-LDS weights (v5 trunk), 80KB LDS -> 2 blocks/CU,
// item-loop logits/DANE (replaces shfl-storm CONSUME), K-region reuse for
// logits/aw/sm. Inputs fp32 dict order; output fp32. Grid 2048 x 512.

typedef short short8 __attribute__((ext_vector_type(8)));
typedef float f32x4 __attribute__((ext_vector_type(4)));
typedef unsigned uint4v __attribute__((ext_vector_type(4)));

__device__ __forceinline__ unsigned bf16r(float x) {
    unsigned u = __float_as_uint(x);
    return (u + 0x7FFFu + ((u >> 16) & 1u)) >> 16;
}
__device__ __forceinline__ unsigned pack2(float a, float b) {
    return bf16r(a) | (bf16r(b) << 16);
}
__device__ __forceinline__ float ubf(unsigned short h) {
    return __uint_as_float(((unsigned)h) << 16);
}
__device__ __forceinline__ float ulo(unsigned u) { return __uint_as_float(u << 16); }
__device__ __forceinline__ float uhi(unsigned u) { return __uint_as_float(u & 0xFFFF0000u); }

// ---------------- kernel 1: per-(side,b,channel) spatial mean of x_low ----------------
__global__ __launch_bounds__(256) void mean_kernel(const float* __restrict__ x_l,
                                                   const float* __restrict__ x_r,
                                                   float* __restrict__ ws_mean) {
    int bid = blockIdx.x;
    const float* src = (bid >= 1024) ? x_r : x_l;
    const float* p = src + (size_t)(bid & 1023) * 16384;
    int t = threadIdx.x;
    float acc = 0.f;
    #pragma unroll 4
    for (int i = t; i < 16384; i += 256) acc += p[i];
    #pragma unroll
    for (int off = 32; off > 0; off >>= 1) acc += __shfl_down(acc, off, 64);
    __shared__ float red[4];
    if ((t & 63) == 0) red[t >> 6] = acc;
    __syncthreads();
    if (t == 0) ws_mean[bid] = (red[0] + red[1] + red[2] + red[3]) * (1.f / 16384.f);
}

// ---------------- kernel 2: channel gate cm[side][b][128] ----------------
__global__ __launch_bounds__(128) void cm_kernel(const float* __restrict__ ws_mean,
                                                 float* __restrict__ ws_cm,
                                                 const float* __restrict__ Wk,
                                                 const float* __restrict__ bk,
                                                 const float* __restrict__ d_w1,
                                                 const float* __restrict__ d_ln2_g,
                                                 const float* __restrict__ d_ln2_b,
                                                 const float* __restrict__ d_w2) {
    int sb = blockIdx.x;
    __shared__ float km[128];
    int o = threadIdx.x;
    const float* mu = ws_mean + sb * 256;
    float acc = bk[o];
    for (int c = 0; c < 256; ++c) acc = fmaf(Wk[o * 256 + c], mu[c], acc);
    km[o] = acc;
    __syncthreads();
    int h = o >> 4, d = o & 15;
    float t1[8];
    #pragma unroll
    for (int r = 0; r < 8; ++r) {
        float a = 0.f;
        #pragma unroll
        for (int dd = 0; dd < 16; ++dd) a = fmaf(d_w1[r * 16 + dd], km[h * 16 + dd], a);
        t1[r] = a / (1.f + expf(-a));
    }
    float m = 0.f;
    #pragma unroll
    for (int r = 0; r < 8; ++r) m += t1[r];
    m *= 0.125f;
    float v = 0.f;
    #pragma unroll
    for (int r = 0; r < 8; ++r) { float df = t1[r] - m; v = fmaf(df, df, v); }
    float rstd = rsqrtf(v * 0.125f + 1e-5f);
    float cmv = 0.f;
    #pragma unroll
    for (int r = 0; r < 8; ++r)
        cmv = fmaf((t1[r] - m) * rstd * d_ln2_g[r] + d_ln2_b[r], d_w2[d * 8 + r], cmv);
    ws_cm[sb * 128 + o] = cmv;
}

// ---------------- kernel 2b: weights -> bf16 pre-swizzled pool in ws ----------------
// pool (u16): WK=0 [4][32][256]; WV=32768; WQ=65536 [2][64][128]; WQV=81920; WP=98304
__global__ __launch_bounds__(256) void wprep(const float* __restrict__ Wq,
                                             const float* __restrict__ Wqv,
                                             const float* __restrict__ Wk,
                                             const float* __restrict__ Wv,
                                             const float* __restrict__ Wp,
                                             unsigned short* __restrict__ wsp) {
    int bid = blockIdx.x, t = threadIdx.x;
    if (bid < 64) {
        const float* src = (bid < 32) ? Wk : Wv;
        unsigned short* dst = wsp + ((bid < 32) ? 0 : 32768);
        int base = (bid & 31) * 1024;
        #pragma unroll
        for (int i = 0; i < 4; ++i) {
            int el = base + t + 256 * i;
            int q = el >> 13, rem = el & 8191, op = rem >> 8, col = rem & 255;
            dst[q * 8192 + op * 256 + (col ^ ((op & 7) << 3))] =
                (unsigned short)bf16r(src[(q * 32 + op) * 256 + col]);
        }
    } else {
        int g = (bid - 64) >> 4;
        const float* src = (g == 0) ? Wq : (g == 1) ? Wqv : Wp;
        unsigned short* dst = wsp + 65536 + g * 16384;
        int base = ((bid - 64) & 15) * 1024;
        #pragma unroll
        for (int i = 0; i < 4; ++i) {
            int el = base + t + 256 * i;
            int hf = el >> 13, rem = el & 8191, op = rem >> 7, col = rem & 127;
            dst[hf * 8192 + op * 128 + (col ^ ((op & 7) << 3))] =
                (unsigned short)bf16r(src[(hf * 64 + op) * 128 + col]);
        }
    }
}

// LDS offsets (u16) — total 40960 u16 = 80 KB exactly (2 blocks/CU)
#define O_XA 0       // 16384: x_low[64][256] / x_high[128][128] / Q-dump / xc / yn
#define O_WB 16384   // 8192: weight stage (quarters/halves are all exactly 8192 u16)
#define O_K  24576   // 8192: K[64][128] u32-swz; after pass1: LG[256][8] @+0, SM f32[512] @+2048
#define O_V  32768   // 8192: V[64][128] frag-swz
#define LDS_U16 40960

__device__ __forceinline__ short8 frag(const unsigned short* lds, int off, int row, int k, int C2) {
    return *(const short8*)&lds[off + row * C2 + (k ^ ((row & 7) << 3))];
}

// stage fp32 activation tile -> bf16 LDS, frag-swizzled, 16B/lane writes
template<int R, int C2>
__device__ __forceinline__ void stageA16(const float* __restrict__ g, size_t cstride,
                                         unsigned short* lds, int off, int t) {
    #pragma unroll
    for (int it = 0; it < (R * (C2 / 8)) / 512; ++it) {
        int idx = t + it * 512;
        int rr = idx & (R - 1);
        int bc = idx / R;
        float v0 = g[(size_t)(8 * bc + 0) * cstride + rr];
        float v1 = g[(size_t)(8 * bc + 1) * cstride + rr];
        float v2 = g[(size_t)(8 * bc + 2) * cstride + rr];
        float v3 = g[(size_t)(8 * bc + 3) * cstride + rr];
        float v4 = g[(size_t)(8 * bc + 4) * cstride + rr];
        float v5 = g[(size_t)(8 * bc + 5) * cstride + rr];
        float v6 = g[(size_t)(8 * bc + 6) * cstride + rr];
        float v7 = g[(size_t)(8 * bc + 7) * cstride + rr];
        uint4v u = {pack2(v0, v1), pack2(v2, v3), pack2(v4, v5), pack2(v6, v7)};
        *(uint4v*)&lds[off + rr * C2 + ((bc ^ (rr & 7)) << 3)] = u;
    }
}

// linear 16KB (8192 u16) copy of pre-swizzled bf16 weights into WB
__device__ __forceinline__ void stageW16(const unsigned short* __restrict__ src,
                                         unsigned short* lds, int t) {
    #pragma unroll
    for (int c = 0; c < 2; ++c) {
        int u = (c * 512 + t) * 8;
        *(short8*)&lds[O_WB + u] = *(const short8*)&src[u];
    }
}

#define ZERO4(A) do { _Pragma("unroll") for (int z_ = 0; z_ < 4; ++z_) A[z_] = (f32x4){0.f,0.f,0.f,0.f}; } while (0)

// 128-row A (XA) x 64-out B (WB half): 4 kc, 4 n-tiles, m-tile = w
#define GEMM4(ACC) do {                                                            \
    _Pragma("unroll")                                                              \
    for (int kc_ = 0; kc_ < 4; ++kc_) {                                            \
      short8 af_ = frag(lds, O_XA, 16 * w + lm, kc_ * 32 + lg * 8, 128);           \
      _Pragma("unroll")                                                            \
      for (int n_ = 0; n_ < 4; ++n_) {                                             \
        short8 bf_ = frag(lds, O_WB, 16 * n_ + lm, kc_ * 32 + lg * 8, 128);        \
        ACC[n_] = __builtin_amdgcn_mfma_f32_16x16x32_bf16(af_, bf_, ACC[n_], 0, 0, 0); \
      } }                                                                          \
  } while (0)

#define COMBINE(ACC, DY, NH) do {                                                  \
    _Pragma("unroll")                                                              \
    for (int n_ = 0; n_ < 4; ++n_) {                                               \
      int nt_ = 4 * (NH) + n_;                                                     \
      int o_ = 16 * nt_ + lm;                                                      \
      float bias_ = bqv[o_];                                                       \
      float cmv_ = cmp[o_];                                                        \
      _Pragma("unroll")                                                            \
      for (int r_ = 0; r_ < 4; ++r_) {                                             \
        int row_ = 16 * w + 4 * lg + r_;                                           \
        int jj_ = row_ >> 1;                                                       \
        float vq_ = ACC[n_][r_] + bias_;                                           \
        float aw_ = ubf(lgp[((DY) * 128 + row_) * 8 + (nt_ ^ (row_ & 7))]);        \
        float vv_ = ubf(lds[O_V + jj_ * 128 + (o_ ^ ((jj_ & 7) << 3))]);           \
        float wg_ = 1.f / (1.f + __expf(-(smk[jj_ * 8 + nt_] + cmv_)));            \
        float xc_ = (1.f - wg_) * aw_ * vv_ * 4.f + wg_ * vq_;                     \
        lds[O_XA + row_ * 128 + (o_ ^ ((row_ & 7) << 3))] = (unsigned short)bf16r(xc_); \
      } } } while (0)

// pass-1 per-dy body (DY must be a literal)
#define PASS1_DY(DY) do {                                                          \
    __syncthreads();                                                               \
    stageA16<128, 128>(hb0 + (DY) * 256, 65536, lds, O_XA, t);                     \
    stageW16(wsp + 65536, lds, t);                                                 \
    __syncthreads();                                                               \
    f32x4 qA[4], qB[4];                                                            \
    ZERO4(qA); GEMM4(qA);                                                          \
    __syncthreads();                                                               \
    stageW16(wsp + 65536 + 8192, lds, t);                                          \
    __syncthreads();                                                               \
    ZERO4(qB); GEMM4(qB);                                                          \
    __syncthreads();                                                               \
    _Pragma("unroll")                                                              \
    for (int n = 0; n < 4; ++n) {                                                  \
      int oA = 16 * n + lm, oB = 64 + 16 * n + lm;                                 \
      float bA = bq[oA], bB = bq[oB];                                              \
      _Pragma("unroll")                                                            \
      for (int r = 0; r < 4; ++r) {                                                \
        int row = 16 * w + 4 * lg + r;                                             \
        lds[O_XA + row * 128 + ((((oA >> 1) ^ (row & 31)) << 1) | (oA & 1))] = (unsigned short)bf16r(qA[n][r] + bA); \
        lds[O_XA + row * 128 + ((((oB >> 1) ^ (row & 31)) << 1) | (oB & 1))] = (unsigned short)bf16r(qB[n][r] + bB); \
      }                                                                            \
    }                                                                              \
    __syncthreads();                                                               \
    _Pragma("unroll")                                                              \
    for (int ii = 0; ii < 2; ++ii) {                                               \
      int h = ih0 + 4 * ii;                                                        \
      int tok = irow >> 1;                                                         \
      float sq = 0.f, sqq = 0.f, sgw = 0.f, sqk = 0.f;                             \
      _Pragma("unroll")                                                            \
      for (int d2 = 0; d2 < 8; ++d2) {                                             \
        unsigned qu = *(const unsigned*)&lds[O_XA + irow * 128 + (((h * 8 + d2) ^ (irow & 31)) << 1)]; \
        unsigned ku = *(const unsigned*)&lds[O_K + tok * 128 + (((h * 8 + d2) ^ (tok & 31)) << 1)];   \
        float q0 = ulo(qu), q1 = uhi(qu);                                          \
        float k0 = ulo(ku), k1 = uhi(ku);                                          \
        sq += q0 + q1;                                                             \
        sqq = fmaf(q0, q0, fmaf(q1, q1, sqq));                                     \
        sgw = fmaf(q0, gwv[2 * d2], fmaf(q1, gwv[2 * d2 + 1], sgw));               \
        sqk = fmaf(q0, k0, fmaf(q1, k1, sqk));                                     \
      }                                                                            \
      lgr[(DY) * 2 + ii] = sqk * 0.25f;                                            \
      float mn = sq * 0.0625f;                                                     \
      float rs = rsqrtf(sqq * 0.0625f - mn * mn + 1e-5f);                          \
      sdacc[ii] += rs * (sgw - mn * S1) + S2;                                      \
    }                                                                              \
  } while (0)

// ---------------- kernel 3: fused main ----------------
__global__ __launch_bounds__(512, 2) void pafm_v8(
    const float* __restrict__ x_l,  const float* __restrict__ x_r,
    const float* __restrict__ x_lh, const float* __restrict__ x_rh,
    const float* __restrict__ bq,   const float* __restrict__ bqv,
    const float* __restrict__ bk,   const float* __restrict__ bv,
    const float* __restrict__ bp,
    const float* __restrict__ ln_g, const float* __restrict__ ln_b,
    const float* __restrict__ d_ln1_g, const float* __restrict__ d_ln1_b,
    const float* __restrict__ d_wsv,
    const float* __restrict__ ws_cm,
    const unsigned short* __restrict__ wsp,
    float* __restrict__ out) {

    __shared__ unsigned short lds[LDS_U16];
    unsigned short* lgp = &lds[O_K];            // logits/aw [256][8] (after pass 1)
    float* smk = (float*)&lds[O_K + 2048];      // sm f32[512]

    int bid = blockIdx.x;                 // s(1)|b(2)|i0(7)|jb(1)
    int s  = bid >> 10;
    int b  = (bid >> 8) & 3;
    int i0 = (bid >> 1) & 127;
    int j0 = (bid & 1) * 64;

    int t = threadIdx.x, w = t >> 6, l = t & 63, lm = l & 15, lg = l >> 4;
    int irow = t & 127, ih0 = t >> 7;

    const float* xlow  = s ? x_r  : x_l;
    const float* xhigh = s ? x_rh : x_lh;
    const float* cmp   = ws_cm + (s * 4 + b) * 128;

    // DANE coefficients (uniform)
    float gwv[16], S1 = 0.f, S2 = 0.f;
    #pragma unroll
    for (int d = 0; d < 16; ++d) {
        float wsd = d_wsv[d];
        gwv[d] = d_ln1_g[d] * wsd;
        S1 += gwv[d];
        S2 += d_ln1_b[d] * wsd;
    }

    const float* lowb = xlow + ((size_t)(b * 256) * 128 + i0) * 128 + j0;
    const float* hb0  = xhigh + ((size_t)(b * 128) * 256 + 2 * i0) * 256 + 2 * j0;

    // ---- KV phase: x_low staged once; 8 weight quarters (4 Wk + 4 Wv) ----
    stageA16<64, 256>(lowb, 16384, lds, O_XA, t);
    int mt = w & 3, ntl = w >> 2;
    #pragma unroll 1
    for (int qq = 0; qq < 8; ++qq) {
        __syncthreads();
        stageW16(wsp + qq * 8192, lds, t);
        __syncthreads();
        f32x4 a = (f32x4){0.f, 0.f, 0.f, 0.f};
        #pragma unroll
        for (int kc = 0; kc < 8; ++kc) {
            short8 af = frag(lds, O_XA, 16 * mt + lm, kc * 32 + lg * 8, 256);
            short8 bf = frag(lds, O_WB, 16 * ntl + lm, kc * 32 + lg * 8, 256);
            a = __builtin_amdgcn_mfma_f32_16x16x32_bf16(af, bf, a, 0, 0, 0);
        }
        int o = (qq & 3) * 32 + 16 * ntl + lm;
        if (qq < 4) {
            float bb = bk[o];
            #pragma unroll
            for (int r = 0; r < 4; ++r) {
                int tok = 16 * mt + 4 * lg + r;
                lds[O_K + tok * 128 + ((((o >> 1) ^ (tok & 31)) << 1) | (o & 1))] =
                    (unsigned short)bf16r(a[r] + bb);
            }
        } else {
            float bb = bv[o];
            #pragma unroll
            for (int r = 0; r < 4; ++r) {
                int tok = 16 * mt + 4 * lg + r;
                lds[O_V + tok * 128 + (o ^ ((tok & 7) << 3))] =
                    (unsigned short)bf16r(a[r] + bb);
            }
        }
    }

    // ---- pass 1: Q GEMM + item-loop logits/DANE (both dy, fully unrolled) ----
    float lgr[4];
    float sdacc[2] = {0.f, 0.f};
    PASS1_DY(0);
    PASS1_DY(1);
    __syncthreads();              // all K reads done -> K region reusable

    // write logits (bf16) + sm (f32) into K region
    #pragma unroll
    for (int ii = 0; ii < 2; ++ii) {
        int h = ih0 + 4 * ii;
        lgp[(0 * 128 + irow) * 8 + (h ^ (irow & 7))] = (unsigned short)bf16r(lgr[0 * 2 + ii]);
        lgp[(1 * 128 + irow) * 8 + (h ^ (irow & 7))] = (unsigned short)bf16r(lgr[1 * 2 + ii]);
        float sdt = sdacc[ii] + __shfl_xor(sdacc[ii], 1, 64);
        if ((t & 1) == 0) smk[(irow >> 1) * 8 + h] = sdt * 0.25f;
    }
    __syncthreads();

    // ---- softmax over 4 px per (jj, h) ----
    {
        int jj = t >> 3, h = t & 7;
        int ra = 2 * jj, rb = 2 * jj + 1;
        int a0 = ra * 8 + (h ^ (ra & 7));
        int a1 = rb * 8 + (h ^ (rb & 7));
        int a2 = (128 + ra) * 8 + (h ^ (ra & 7));
        int a3 = (128 + rb) * 8 + (h ^ (rb & 7));
        float l0 = ubf(lgp[a0]), l1 = ubf(lgp[a1]), l2 = ubf(lgp[a2]), l3 = ubf(lgp[a3]);
        float mx = fmaxf(fmaxf(l0, l1), fmaxf(l2, l3));
        float e0 = __expf(l0 - mx), e1 = __expf(l1 - mx);
        float e2 = __expf(l2 - mx), e3 = __expf(l3 - mx);
        float inv = 1.f / (e0 + e1 + e2 + e3);
        lgp[a0] = (unsigned short)bf16r(e0 * inv);
        lgp[a1] = (unsigned short)bf16r(e1 * inv);
        lgp[a2] = (unsigned short)bf16r(e2 * inv);
        lgp[a3] = (unsigned short)bf16r(e3 * inv);
    }

    // ---- pass 2 per dy: VQ -> combine -> P -> LN -> store ----
    #pragma unroll 1
    for (int dy = 0; dy < 2; ++dy) {
        __syncthreads();
        stageA16<128, 128>(hb0 + dy * 256, 65536, lds, O_XA, t);
        stageW16(wsp + 81920, lds, t);          // WQV half 0
        __syncthreads();
        f32x4 vqA[4], vqB[4];
        ZERO4(vqA); GEMM4(vqA);
        __syncthreads();
        stageW16(wsp + 81920 + 8192, lds, t);   // WQV half 1
        __syncthreads();
        ZERO4(vqB); GEMM4(vqB);
        __syncthreads();                        // VQ reads of XA done
        COMBINE(vqA, dy, 0);
        COMBINE(vqB, dy, 1);
        stageW16(wsp + 98304, lds, t);          // WP half 0 (WB free since barrier)
        __syncthreads();                        // xc + WP visible

        f32x4 pA[4], pB[4];
        ZERO4(pA); GEMM4(pA);
        __syncthreads();
        stageW16(wsp + 98304 + 8192, lds, t);   // WP half 1
        __syncthreads();
        ZERO4(pB); GEMM4(pB);
        __syncthreads();                        // P reads of XA done

        float mean_[4], rstd_[4];
        #pragma unroll
        for (int r = 0; r < 4; ++r) {
            float ps = 0.f, pq = 0.f;
            #pragma unroll
            for (int n = 0; n < 4; ++n) {
                float y0 = pA[n][r] + bp[16 * n + lm];
                float y1 = pB[n][r] + bp[64 + 16 * n + lm];
                ps += y0 + y1;
                pq = fmaf(y0, y0, pq); pq = fmaf(y1, y1, pq);
            }
            #pragma unroll
            for (int d = 1; d < 16; d <<= 1) { ps += __shfl_xor(ps, d, 64); pq += __shfl_xor(pq, d, 64); }
            float mn = ps * (1.f / 128.f);
            mean_[r] = mn;
            rstd_[r] = rsqrtf(pq * (1.f / 128.f) - mn * mn + 1e-5f);
        }
        // yn -> XA (u32-pair swizzle)
        #pragma unroll
        for (int n = 0; n < 4; ++n) {
            int oA = 16 * n + lm, oB = 64 + 16 * n + lm;
            float gA = ln_g[oA], bA = ln_b[oA], biA = bp[oA];
            float gB = ln_g[oB], bB = ln_b[oB], biB = bp[oB];
            #pragma unroll
            for (int r = 0; r < 4; ++r) {
                int row = 16 * w + 4 * lg + r;
                float ynA = (pA[n][r] + biA - mean_[r]) * rstd_[r] * gA + bA;
                float ynB = (pB[n][r] + biB - mean_[r]) * rstd_[r] * gB + bB;
                lds[O_XA + row * 128 + ((((oA >> 1) ^ (row & 31)) << 1) | (oA & 1))] = (unsigned short)bf16r(ynA);
                lds[O_XA + row * 128 + ((((oB >> 1) ^ (row & 31)) << 1) | (oB & 1))] = (unsigned short)bf16r(ynB);
            }
        }
        __syncthreads();
        // coalesced store + residual (global, L2-hot)
        {
            const float* rb = hb0 + dy * 256;
            float* ob = out + (size_t)s * 33554432
                      + ((size_t)(b * 128)) * 65536 + (size_t)(2 * i0 + dy) * 256 + 2 * j0;
            int ph = t & 127, cq = t >> 7;
            #pragma unroll
            for (int it = 0; it < 16; ++it) {
                int c4 = it * 4 + cq;
                unsigned uv = *(const unsigned*)&lds[O_XA + ph * 128 + ((c4 ^ (ph & 31)) << 1)];
                size_t off0 = (size_t)(2 * c4) * 65536 + ph;
                size_t off1 = off0 + 65536;
                ob[off0] = rb[off0] + ulo(uv);
                ob[off1] = rb[off1] + uhi(uv);
            }
        }
    }
}

extern "C" void kernel_launch(void* const* d_in, const int* in_sizes, int n_in,
                              void* d_out, int out_size, void* d_ws, size_t ws_size,
                              hipStream_t stream) {
    const float* x_l   = (const float*)d_in[0];
    const float* x_r   = (const float*)d_in[1];
    const float* x_lh  = (const float*)d_in[2];
    const float* x_rh  = (const float*)d_in[3];
    const float* Wq    = (const float*)d_in[4];
    const float* bq    = (const float*)d_in[5];
    const float* Wqv   = (const float*)d_in[6];
    const float* bqv   = (const float*)d_in[7];
    const float* Wk    = (const float*)d_in[8];
    const float* bk    = (const float*)d_in[9];
    const float* Wv    = (const float*)d_in[10];
    const float* bv    = (const float*)d_in[11];
    const float* Wp    = (const float*)d_in[12];
    const float* bp    = (const float*)d_in[13];
    const float* ln_g  = (const float*)d_in[14];
    const float* ln_b  = (const float*)d_in[15];
    const float* dln1g = (const float*)d_in[16];
    const float* dln1b = (const float*)d_in[17];
    const float* d_wsv = (const float*)d_in[18];
    const float* d_w1  = (const float*)d_in[19];
    const float* dln2g = (const float*)d_in[20];
    const float* dln2b = (const float*)d_in[21];
    const float* d_w2  = (const float*)d_in[22];

    float* out = (float*)d_out;
    float* ws_mean = (float*)d_ws;                                 // 2048 f
    float* ws_cm   = ws_mean + 2048;                               // 1024 f
    unsigned short* wsp = (unsigned short*)((char*)d_ws + 16384);  // 224 KB bf16 pool

    mean_kernel<<<2048, 256, 0, stream>>>(x_l, x_r, ws_mean);
    wprep<<<112, 256, 0, stream>>>(Wq, Wqv, Wk, Wv, Wp, wsp);
    cm_kernel<<<8, 128, 0, stream>>>(ws_mean, ws_cm, Wk, bk, d_w1, dln2g, dln2b, d_w2);
    pafm_v8<<<2048, 512, 0, stream>>>(x_l, x_r, x_lh, x_rh,
                                      bq, bqv, bk, bv, bp, ln_g, ln_b,
                                      dln1g, dln1b, d_wsv, ws_cm, wsp, out);
}